// Round 11
// baseline (252.115 us; speedup 1.0000x reference)
//
#include <hip/hip_runtime.h>
#include <hip/hip_fp16.h>

#define EPB 4096        // edges per bin-scatter block
#define SEGCAP 12288    // LDS staging cap for one coarse bucket's edges

typedef __attribute__((ext_vector_type(8))) _Float16 half8;
typedef __attribute__((ext_vector_type(4))) float f32x4;
typedef __attribute__((ext_vector_type(4))) int i32x4;

// ---------------- generic scan helpers ----------------------------------------

__global__ void scan1(const int* __restrict__ v, int* __restrict__ incl,
                      int* __restrict__ bsum, int n) {
    __shared__ int tmp[256];
    int t = threadIdx.x;
    int gid = blockIdx.x * 256 + t;
    tmp[t] = (gid < n) ? v[gid] : 0;
    __syncthreads();
    for (int off = 1; off < 256; off <<= 1) {
        int x = (t >= off) ? tmp[t - off] : 0;
        __syncthreads();
        tmp[t] += x;
        __syncthreads();
    }
    if (gid < n) incl[gid] = tmp[t];
    if (t == 255) bsum[blockIdx.x] = tmp[255];
}

__global__ void scan2(const int* __restrict__ bsum, int* __restrict__ boff, int nb) {
    __shared__ int tmp[1024];
    int t = threadIdx.x;
    int orig = (t < nb) ? bsum[t] : 0;
    tmp[t] = orig;
    __syncthreads();
    for (int off = 1; off < 1024; off <<= 1) {
        int x = (t >= off) ? tmp[t - off] : 0;
        __syncthreads();
        tmp[t] += x;
        __syncthreads();
    }
    if (t < nb) boff[t] = tmp[t] - orig;
}

__global__ void basec_k(const int* __restrict__ incl, const int* __restrict__ boff,
                        const int* __restrict__ hist, int* __restrict__ base, int T) {
    int i = blockIdx.x * 256 + threadIdx.x;
    if (i < T) base[i] = incl[i] + boff[blockIdx.x] - hist[i];
}

// ---------------- pass 0: coarse histogram [bucket][block] --------------------

__global__ __launch_bounds__(256) void hist_k(const int* __restrict__ dst,
                                              int* __restrict__ hist,
                                              int E, int nblk, int nbuk) {
    __shared__ int h[512];
    int t = threadIdx.x;
    for (int i = t; i < nbuk; i += 256) h[i] = 0;
    __syncthreads();
    int start = blockIdx.x * EPB;
    int end = start + EPB; if (end > E) end = E;
    if (end - start == EPB) {
        const i32x4* dv = (const i32x4*)(dst + start);
#pragma unroll
        for (int p = 0; p < EPB / 1024; ++p) {
            i32x4 d4 = dv[t + p * 256];
            atomicAdd(&h[d4.x >> 8], 1);
            atomicAdd(&h[d4.y >> 8], 1);
            atomicAdd(&h[d4.z >> 8], 1);
            atomicAdd(&h[d4.w >> 8], 1);
        }
    } else {
        for (int e = start + t; e < end; e += 256) atomicAdd(&h[dst[e] >> 8], 1);
    }
    __syncthreads();
    for (int i = t; i < nbuk; i += 256) hist[i * nblk + blockIdx.x] = h[i];
}

// ---------------- pass 1: bin-scatter with LDS reorder ------------------------

__global__ __launch_bounds__(256) void binscatter_k(const int* __restrict__ src,
                                                    const int* __restrict__ dst,
                                                    const int* __restrict__ base,
                                                    unsigned int* __restrict__ binned,
                                                    int E, int nblk, int nbuk) {
    __shared__ int hloc[512];
    __shared__ int lstart[512];
    __shared__ int stmp[512];
    __shared__ unsigned int pk[EPB];
    __shared__ unsigned short bid[EPB];
    int t = threadIdx.x;
    int blk = blockIdx.x;
    int start = blk * EPB;
    int end = start + EPB; if (end > E) end = E;
    int cntE = end - start;

    for (int i = t; i < nbuk; i += 256) hloc[i] = 0;
    __syncthreads();
    for (int e = start + t; e < end; e += 256) atomicAdd(&hloc[dst[e] >> 8], 1);
    __syncthreads();
    for (int i = t; i < 512; i += 256) stmp[i] = (i < nbuk) ? hloc[i] : 0;
    __syncthreads();
    for (int off = 1; off < 512; off <<= 1) {
        int v0 = (t >= off) ? stmp[t - off] : 0;
        int v1 = stmp[t + 256 - off];
        __syncthreads();
        stmp[t] += v0;
        stmp[t + 256] += v1;
        __syncthreads();
    }
    for (int i = t; i < nbuk; i += 256) {
        int ex = stmp[i] - hloc[i];
        lstart[i] = ex;
        hloc[i] = ex;
    }
    __syncthreads();
    for (int e = start + t; e < end; e += 256) {
        int d = dst[e];
        int b = d >> 8;
        int r = atomicAdd(&hloc[b], 1);
        pk[r] = (unsigned int)src[e] | ((unsigned int)(d & 255) << 24);
        bid[r] = (unsigned short)b;
    }
    __syncthreads();
    for (int i = t; i < cntE; i += 256) {
        int b = bid[i];
        binned[base[b * nblk + blk] + (i - lstart[b])] = pk[i];
    }
}

// ---------------- pass 2: per-bucket counting sort -> rowptr, dinv, col --------

__global__ __launch_bounds__(256) void group_k(const unsigned int* __restrict__ binned,
                                               const int* __restrict__ base,
                                               int* __restrict__ rowptr,
                                               float* __restrict__ dinv,
                                               int* __restrict__ col,
                                               int nblk, int nbuk, int N, int E) {
    __shared__ int cntL[256];
    __shared__ int sc[256];
    __shared__ int cur[256];
    __shared__ int stage[SEGCAP];
    int b = blockIdx.x, t = threadIdx.x;
    int segstart = base[b * nblk];
    int segend = (b + 1 < nbuk) ? base[(b + 1) * nblk] : E;
    int seglen = segend - segstart;

    cntL[t] = 0;
    __syncthreads();
    for (int i = segstart + t; i < segend; i += 256)
        atomicAdd(&cntL[binned[i] >> 24], 1);
    __syncthreads();
    sc[t] = cntL[t];
    __syncthreads();
    for (int off = 1; off < 256; off <<= 1) {
        int v = (t >= off) ? sc[t - off] : 0;
        __syncthreads();
        sc[t] += v;
        __syncthreads();
    }
    int n = (b << 8) + t;
    if (n < N) {
        rowptr[n + 1] = segstart + sc[t];
        dinv[n] = rsqrtf((float)cntL[t] + 1.0f);
    }
    if (b == 0 && t == 0) rowptr[0] = 0;
    cur[t] = sc[t] - cntL[t];
    __syncthreads();
    if (seglen <= SEGCAP) {
        for (int i = segstart + t; i < segend; i += 256) {
            unsigned int p = binned[i];
            int r = atomicAdd(&cur[p >> 24], 1);
            stage[r] = (int)(p & 0xFFFFFFu);
        }
        __syncthreads();
        for (int i = t; i < seglen; i += 256) col[segstart + i] = stage[i];
    } else {
        for (int i = segstart + t; i < segend; i += 256) {
            unsigned int p = binned[i];
            int r = atomicAdd(&cur[p >> 24], 1);
            col[segstart + r] = (int)(p & 0xFFFFFFu);
        }
    }
}

// ------- pack W1,W2 (f32 [128][128]) into fp16 MFMA B-fragment order -----------

__global__ __launch_bounds__(256) void packW2_k(const float* __restrict__ W1,
                                                const float* __restrict__ W2,
                                                _Float16* __restrict__ Wp1,
                                                _Float16* __restrict__ Wp2) {
    const float* W = (blockIdx.x < 8) ? W1 : W2;
    _Float16* Wp = (blockIdx.x < 8) ? Wp1 : Wp2;
    int t = (blockIdx.x & 7) * 256 + threadIdx.x;   // 0..2047
    int lane = t & 63, qct = t >> 6;
    int q = qct >> 3, ct = qct & 7;
    int krow = q * 32 + (lane >> 4) * 8;
    int c = ct * 16 + (lane & 15);
#pragma unroll
    for (int j = 0; j < 8; ++j)
        Wp[(size_t)t * 8 + j] = (_Float16)W[(krow + j) * 128 + c];
}

// ------- MFMA GEMM: G = (X @ W) * dinv[row] -> fp16 [N][128] ------------------

template<typename XT>
__global__ __launch_bounds__(256) void gemm_mfma(const XT* __restrict__ X,
                                                 const _Float16* __restrict__ Wp,
                                                 const float* __restrict__ dinv,
                                                 _Float16* __restrict__ Gh, int M) {
    constexpr bool F32 = (sizeof(XT) == 4);
    __shared__ _Float16 Wl[16384];
    int t = threadIdx.x;
    for (int i = t; i < 2048; i += 256)
        *(float4*)&Wl[(size_t)i * 8] = ((const float4*)Wp)[i];

    int wid = t >> 6, lane = t & 63;
    int row0 = blockIdx.x * 64 + wid * 16;
    int arow = row0 + (lane & 15); if (arow >= M) arow = M - 1;
    int kgrp = (lane >> 4) * 8;

    half8 a[4];
    if constexpr (F32) {
#pragma unroll
        for (int q = 0; q < 4; ++q) {
            const float* p = (const float*)X + (size_t)arow * 128 + q * 32 + kgrp;
            float4 u = *(const float4*)p;
            float4 v = *(const float4*)(p + 4);
            half8 h;
            h[0] = (_Float16)u.x; h[1] = (_Float16)u.y;
            h[2] = (_Float16)u.z; h[3] = (_Float16)u.w;
            h[4] = (_Float16)v.x; h[5] = (_Float16)v.y;
            h[6] = (_Float16)v.z; h[7] = (_Float16)v.w;
            a[q] = h;
        }
    } else {
#pragma unroll
        for (int q = 0; q < 4; ++q)
            a[q] = *(const half8*)((const _Float16*)X + (size_t)arow * 128 + q * 32 + kgrp);
    }
    __syncthreads();

    f32x4 acc[8];
#pragma unroll
    for (int ct = 0; ct < 8; ++ct) acc[ct] = (f32x4){0.f, 0.f, 0.f, 0.f};

#pragma unroll
    for (int q = 0; q < 4; ++q) {
#pragma unroll
        for (int ct = 0; ct < 8; ++ct) {
            half8 b = *(const half8*)&Wl[(size_t)((q * 8 + ct) * 64 + lane) * 8];
            acc[ct] = __builtin_amdgcn_mfma_f32_16x16x32_f16(a[q], b, acc[ct], 0, 0, 0);
        }
    }

    int rbase = row0 + (lane >> 4) * 4;
#pragma unroll
    for (int reg = 0; reg < 4; ++reg) {
        int r = rbase + reg;
        if (r < M) {
            float di = dinv[r];
#pragma unroll
            for (int ct = 0; ct < 8; ++ct)
                Gh[(size_t)r * 128 + ct * 16 + (lane & 15)] = (_Float16)(acc[ct][reg] * di);
        }
    }
}

// ------- helpers ----------------------------------------------------------------

__device__ __forceinline__ void addpk(__half2* acc, float4 v) {
    const __half2* h = reinterpret_cast<const __half2*>(&v);
#pragma unroll
    for (int j = 0; j < 4; ++j) acc[j] = __hadd2(acc[j], h[j]);
}

// ------- FUSED: layer-1 aggregate (relu) -> LDS -> layer-2 MFMA -> G2 -----------
// Each wave aggregates 16 nodes into LDS rows (136 halves pitch), then MFMAs
// them against W2 fragments read directly from global (L1-resident 32KB).

__global__ __launch_bounds__(256) void agg_gemm(const float4* __restrict__ G4,
                                                const float* __restrict__ dinv,
                                                const int* __restrict__ rowptr,
                                                const int* __restrict__ col,
                                                const float4* __restrict__ bias4,
                                                const _Float16* __restrict__ Wp,
                                                _Float16* __restrict__ Gout, int N) {
    __shared__ _Float16 Hl[64 * 136];   // 17.4 KB, padded rows (bank-safe)
    int t = threadIdx.x;
    int wid = t >> 6, lane = t & 63;
    int f = lane & 15;
    int slot = lane >> 4;
    int row0 = blockIdx.x * 64;

    for (int i = 0; i < 16; ++i) {
        int n = row0 + wid * 16 + i;
        if (n >= N) n = N - 1;
        int e0 = rowptr[n], e1 = rowptr[n + 1];
        __half2 acc[4];
#pragma unroll
        for (int j = 0; j < 4; ++j) acc[j] = __float2half2_rn(0.f);
        int base = e0;
        for (; base + 16 <= e1; base += 16) {
            int s0 = col[base + slot];
            int s1 = col[base + 4 + slot];
            int s2 = col[base + 8 + slot];
            int s3 = col[base + 12 + slot];
            float4 v0 = G4[(size_t)s0 * 16 + f];
            float4 v1 = G4[(size_t)s1 * 16 + f];
            float4 v2 = G4[(size_t)s2 * 16 + f];
            float4 v3 = G4[(size_t)s3 * 16 + f];
            addpk(acc, v0); addpk(acc, v1); addpk(acc, v2); addpk(acc, v3);
        }
        for (int idx = base + slot; idx < e1; idx += 4) {
            float4 v = G4[(size_t)col[idx] * 16 + f];
            addpk(acc, v);
        }
        float a[8];
#pragma unroll
        for (int j = 0; j < 4; ++j) {
            float2 fp = __half22float2(acc[j]);
            a[2 * j] = fp.x;
            a[2 * j + 1] = fp.y;
        }
#pragma unroll
        for (int j = 0; j < 8; ++j) {
            a[j] += __shfl_xor(a[j], 16);
            a[j] += __shfl_xor(a[j], 32);
        }
        if (slot == 0) {
            float4 g = G4[(size_t)n * 16 + f];
            const __half2* sp = (const __half2*)&g;
            float di = dinv[n];
            float4 b0 = bias4[f * 2], b1 = bias4[f * 2 + 1];
            float o[8];
#pragma unroll
            for (int j = 0; j < 4; ++j) {
                float2 fp = __half22float2(sp[j]);
                o[2 * j]     = di * (a[2 * j] + fp.x);
                o[2 * j + 1] = di * (a[2 * j + 1] + fp.y);
            }
            o[0] += b0.x; o[1] += b0.y; o[2] += b0.z; o[3] += b0.w;
            o[4] += b1.x; o[5] += b1.y; o[6] += b1.z; o[7] += b1.w;
#pragma unroll
            for (int j = 0; j < 8; ++j) o[j] = fmaxf(o[j], 0.f);
            __half2 hh[4];
#pragma unroll
            for (int j = 0; j < 4; ++j) hh[j] = __floats2half2_rn(o[2 * j], o[2 * j + 1]);
            *(float4*)&Hl[(size_t)(wid * 16 + i) * 136 + f * 8] = *(float4*)hh;
        }
    }
    __syncthreads();

    // MFMA phase: A from LDS, B fragments from global (L1-hot)
    int arowl = wid * 16 + (lane & 15);
    int kgrp = (lane >> 4) * 8;
    half8 av[4];
#pragma unroll
    for (int q = 0; q < 4; ++q)
        av[q] = *(const half8*)&Hl[(size_t)arowl * 136 + q * 32 + kgrp];

    f32x4 accm[8];
#pragma unroll
    for (int ct = 0; ct < 8; ++ct) accm[ct] = (f32x4){0.f, 0.f, 0.f, 0.f};
#pragma unroll
    for (int q = 0; q < 4; ++q) {
#pragma unroll
        for (int ct = 0; ct < 8; ++ct) {
            half8 b = *(const half8*)&Wp[(size_t)((q * 8 + ct) * 64 + lane) * 8];
            accm[ct] = __builtin_amdgcn_mfma_f32_16x16x32_f16(av[q], b, accm[ct], 0, 0, 0);
        }
    }
    int rbase = row0 + wid * 16 + (lane >> 4) * 4;
#pragma unroll
    for (int reg = 0; reg < 4; ++reg) {
        int r = rbase + reg;
        if (r < N) {
            float di = dinv[r];
#pragma unroll
            for (int ct = 0; ct < 8; ++ct)
                Gout[(size_t)r * 128 + ct * 16 + (lane & 15)] =
                    (_Float16)(accm[ct][reg] * di);
        }
    }
}

// ------- layer-2 aggregate with FUSED layer-3 transform ------------------------

__global__ __launch_bounds__(256) void aggregate128h_w3(const float4* __restrict__ G4,
                                                        const float* __restrict__ dinv,
                                                        const int* __restrict__ rowptr,
                                                        const int* __restrict__ col,
                                                        const float4* __restrict__ bias4,
                                                        const float* __restrict__ W3,
                                                        float* __restrict__ G3, int N) {
    int n = blockIdx.x * 4 + (threadIdx.x >> 6);
    if (n >= N) return;
    int lane = threadIdx.x & 63;
    int f = lane & 15;
    int slot = lane >> 4;
    int e0 = rowptr[n], e1 = rowptr[n + 1];
    __half2 acc[4];
#pragma unroll
    for (int j = 0; j < 4; ++j) acc[j] = __float2half2_rn(0.f);

    int base = e0;
    for (; base + 16 <= e1; base += 16) {
        int s0 = col[base + slot];
        int s1 = col[base + 4 + slot];
        int s2 = col[base + 8 + slot];
        int s3 = col[base + 12 + slot];
        float4 v0 = G4[(size_t)s0 * 16 + f];
        float4 v1 = G4[(size_t)s1 * 16 + f];
        float4 v2 = G4[(size_t)s2 * 16 + f];
        float4 v3 = G4[(size_t)s3 * 16 + f];
        addpk(acc, v0); addpk(acc, v1); addpk(acc, v2); addpk(acc, v3);
    }
    for (int idx = base + slot; idx < e1; idx += 4) {
        float4 v = G4[(size_t)col[idx] * 16 + f];
        addpk(acc, v);
    }
    float a[8];
#pragma unroll
    for (int j = 0; j < 4; ++j) {
        float2 fp = __half22float2(acc[j]);
        a[2 * j] = fp.x;
        a[2 * j + 1] = fp.y;
    }
#pragma unroll
    for (int j = 0; j < 8; ++j) {
        a[j] += __shfl_xor(a[j], 16);
        a[j] += __shfl_xor(a[j], 32);
    }
    float p0 = 0.f, p1 = 0.f;
    float di = dinv[n];
    if (slot == 0) {
        float4 g = G4[(size_t)n * 16 + f];
        const __half2* sp = (const __half2*)&g;
        float4 b0 = bias4[f * 2], b1 = bias4[f * 2 + 1];
        float o[8];
#pragma unroll
        for (int j = 0; j < 4; ++j) {
            float2 fp = __half22float2(sp[j]);
            o[2 * j]     = di * (a[2 * j] + fp.x);
            o[2 * j + 1] = di * (a[2 * j + 1] + fp.y);
        }
        o[0] += b0.x; o[1] += b0.y; o[2] += b0.z; o[3] += b0.w;
        o[4] += b1.x; o[5] += b1.y; o[6] += b1.z; o[7] += b1.w;
#pragma unroll
        for (int j = 0; j < 8; ++j) o[j] = fmaxf(o[j], 0.f);
        float w[16];
        *(float4*)&w[0]  = ((const float4*)W3)[f * 4 + 0];
        *(float4*)&w[4]  = ((const float4*)W3)[f * 4 + 1];
        *(float4*)&w[8]  = ((const float4*)W3)[f * 4 + 2];
        *(float4*)&w[12] = ((const float4*)W3)[f * 4 + 3];
#pragma unroll
        for (int j = 0; j < 8; ++j) {
            p0 += o[j] * w[2 * j];
            p1 += o[j] * w[2 * j + 1];
        }
    }
#pragma unroll
    for (int m = 1; m < 16; m <<= 1) {
        p0 += __shfl_xor(p0, m);
        p1 += __shfl_xor(p1, m);
    }
    if (lane == 0) {
        G3[(size_t)n * 2 + 0] = p0 * di;
        G3[(size_t)n * 2 + 1] = p1 * di;
    }
}

// -------- fused layer-3 aggregate + mean-pool ---------------------------------

__global__ __launch_bounds__(256) void agg2pool(const float2* __restrict__ G3,
                                                const float* __restrict__ dinv,
                                                const int* __restrict__ rowptr,
                                                const int* __restrict__ col,
                                                const float* __restrict__ b3,
                                                const int* __restrict__ batch,
                                                float* __restrict__ pool, int N) {
    __shared__ float ls[192];
    for (int i = threadIdx.x; i < 192; i += 256) ls[i] = 0.f;
    __syncthreads();
    int n = blockIdx.x * 256 + threadIdx.x;
    if (n < N) {
        float s0 = 0.f, s1 = 0.f;
        int e0 = rowptr[n], e1 = rowptr[n + 1];
        int e = e0;
        for (; e + 4 <= e1; e += 4) {
            float2 v0 = G3[col[e]];
            float2 v1 = G3[col[e + 1]];
            float2 v2 = G3[col[e + 2]];
            float2 v3 = G3[col[e + 3]];
            s0 += v0.x + v1.x + v2.x + v3.x;
            s1 += v0.y + v1.y + v2.y + v3.y;
        }
        for (; e < e1; ++e) {
            float2 v = G3[col[e]];
            s0 += v.x; s1 += v.y;
        }
        float2 g = G3[n];
        float di = dinv[n];
        float o0 = di * (s0 + g.x) + b3[0];
        float o1 = di * (s1 + g.y) + b3[1];
        int gb = batch[n];
        atomicAdd(&ls[gb * 3 + 0], o0);
        atomicAdd(&ls[gb * 3 + 1], o1);
        atomicAdd(&ls[gb * 3 + 2], 1.0f);
    }
    __syncthreads();
    for (int i = threadIdx.x; i < 192; i += 256)
        if (ls[i] != 0.f) atomicAdd(&pool[i], ls[i]);
}

__global__ void finalize_k(const float* __restrict__ pool, float* __restrict__ out) {
    int t = threadIdx.x;
    if (t < 128) {
        int g = t >> 1, c = t & 1;
        out[t] = pool[g * 3 + c] / fmaxf(pool[g * 3 + 2], 1.0f);
    }
}

// ---------------- launch --------------------------------------------------------

extern "C" void kernel_launch(void* const* d_in, const int* in_sizes, int n_in,
                              void* d_out, int out_size, void* d_ws, size_t ws_size,
                              hipStream_t stream) {
    const float* x   = (const float*)d_in[0];
    const int*  edge = (const int*)d_in[1];
    const int*  batch= (const int*)d_in[2];
    const float* W1  = (const float*)d_in[3];
    const float* b1  = (const float*)d_in[4];
    const float* W2  = (const float*)d_in[5];
    const float* b2  = (const float*)d_in[6];
    const float* W3  = (const float*)d_in[7];
    const float* b3  = (const float*)d_in[8];
    float* out = (float*)d_out;

    int N = in_sizes[0] / 128;
    int E = in_sizes[1] / 2;
    const int* src = edge;
    const int* dst = edge + E;

    int nblk1 = (E + EPB - 1) / EPB;
    int nbuk  = (N + 255) >> 8;
    int T     = nbuk * nblk1;
    int nb2   = (T + 255) / 256;

    char* base_ws = (char*)d_ws;
    size_t off = 0;
    auto alloc = [&](size_t bytes) -> void* {
        void* r = base_ws + off;
        off = (off + bytes + 255) & ~(size_t)255;
        return r;
    };
    _Float16*     GhA    = (_Float16*)alloc((size_t)N * 128 * 2);
    _Float16*     GhB    = (_Float16*)alloc((size_t)N * 128 * 2);
    _Float16*     Wp1    = (_Float16*)alloc(16384 * 2);
    _Float16*     Wp2    = (_Float16*)alloc(16384 * 2);
    float*        dinv   = (float*)alloc((size_t)N * 4);
    int*          rowptr = (int*)alloc((size_t)(N + 1) * 4);
    int*          col    = (int*)alloc((size_t)E * 4);
    unsigned int* binned = (unsigned int*)alloc((size_t)E * 4);
    int*          hist   = (int*)alloc((size_t)T * 4);
    int*          incl   = (int*)alloc((size_t)T * 4);
    int*          bsum   = (int*)alloc(1024 * 4);
    int*          boff   = (int*)alloc(1024 * 4);
    int*          basea  = (int*)alloc((size_t)(T + 1) * 4);
    float*        g3     = (float*)alloc((size_t)N * 2 * 4);
    float*        pool   = (float*)alloc(64 * 3 * 4);

    hipMemsetAsync(pool, 0, 64 * 3 * 4, stream);

    // W pre-packing for MFMA (single launch)
    packW2_k<<<16, 256, 0, stream>>>(W1, W2, Wp1, Wp2);

    // CSR build via 2-level bucket sort
    hist_k<<<nblk1, 256, 0, stream>>>(dst, hist, E, nblk1, nbuk);
    scan1<<<nb2, 256, 0, stream>>>(hist, incl, bsum, T);
    scan2<<<1, 1024, 0, stream>>>(bsum, boff, nb2);
    basec_k<<<nb2, 256, 0, stream>>>(incl, boff, hist, basea, T);
    binscatter_k<<<nblk1, 256, 0, stream>>>(src, dst, basea, binned, E, nblk1, nbuk);
    group_k<<<nbuk, 256, 0, stream>>>(binned, basea, rowptr, dinv, col, nblk1, nbuk, N, E);

    int gb = (N + 63) / 64;
    int ab = (N + 3) / 4;

    // layer 1 GEMM (f32 input, MFMA)
    gemm_mfma<float><<<gb, 256, 0, stream>>>(x, Wp1, dinv, GhA, N);
    // fused layer-1 aggregate + layer-2 GEMM
    agg_gemm<<<gb, 256, 0, stream>>>((const float4*)GhA, dinv, rowptr, col,
                                     (const float4*)b1, Wp2, GhB, N);
    // layer-2 aggregate with fused layer-3 transform
    aggregate128h_w3<<<ab, 256, 0, stream>>>((const float4*)GhB, dinv, rowptr, col,
                                             (const float4*)b2, W3, g3, N);
    // layer 3 aggregate + pool (fused)
    agg2pool<<<(N + 255) / 256, 256, 0, stream>>>((const float2*)g3, dinv, rowptr, col,
                                                  b3, batch, pool, N);
    finalize_k<<<1, 128, 0, stream>>>(pool, out);
}

// Round 12
// 241.604 us; speedup vs baseline: 1.0435x; 1.0435x over previous
//
#include <hip/hip_runtime.h>
#include <hip/hip_fp16.h>

#define EPB 4096        // edges per bin-scatter block
#define SEGCAP 12288    // LDS staging cap for one coarse bucket's edges

typedef __attribute__((ext_vector_type(8))) _Float16 half8;
typedef __attribute__((ext_vector_type(4))) float f32x4;
typedef __attribute__((ext_vector_type(4))) int i32x4;

// ---------------- generic scan helpers ----------------------------------------

__global__ void scan1(const int* __restrict__ v, int* __restrict__ incl,
                      int* __restrict__ bsum, int n) {
    __shared__ int tmp[256];
    int t = threadIdx.x;
    int gid = blockIdx.x * 256 + t;
    tmp[t] = (gid < n) ? v[gid] : 0;
    __syncthreads();
    for (int off = 1; off < 256; off <<= 1) {
        int x = (t >= off) ? tmp[t - off] : 0;
        __syncthreads();
        tmp[t] += x;
        __syncthreads();
    }
    if (gid < n) incl[gid] = tmp[t];
    if (t == 255) bsum[blockIdx.x] = tmp[255];
}

__global__ void scan2(const int* __restrict__ bsum, int* __restrict__ boff, int nb) {
    __shared__ int tmp[1024];
    int t = threadIdx.x;
    int orig = (t < nb) ? bsum[t] : 0;
    tmp[t] = orig;
    __syncthreads();
    for (int off = 1; off < 1024; off <<= 1) {
        int x = (t >= off) ? tmp[t - off] : 0;
        __syncthreads();
        tmp[t] += x;
        __syncthreads();
    }
    if (t < nb) boff[t] = tmp[t] - orig;
}

__global__ void basec_k(const int* __restrict__ incl, const int* __restrict__ boff,
                        const int* __restrict__ hist, int* __restrict__ base, int T) {
    int i = blockIdx.x * 256 + threadIdx.x;
    if (i < T) base[i] = incl[i] + boff[blockIdx.x] - hist[i];
}

// ---------------- pass 0: coarse histogram [bucket][block] --------------------

__global__ __launch_bounds__(256) void hist_k(const int* __restrict__ dst,
                                              int* __restrict__ hist,
                                              int E, int nblk, int nbuk) {
    __shared__ int h[512];
    int t = threadIdx.x;
    for (int i = t; i < nbuk; i += 256) h[i] = 0;
    __syncthreads();
    int start = blockIdx.x * EPB;
    int end = start + EPB; if (end > E) end = E;
    if (end - start == EPB) {
        const i32x4* dv = (const i32x4*)(dst + start);
#pragma unroll
        for (int p = 0; p < EPB / 1024; ++p) {
            i32x4 d4 = dv[t + p * 256];
            atomicAdd(&h[d4.x >> 8], 1);
            atomicAdd(&h[d4.y >> 8], 1);
            atomicAdd(&h[d4.z >> 8], 1);
            atomicAdd(&h[d4.w >> 8], 1);
        }
    } else {
        for (int e = start + t; e < end; e += 256) atomicAdd(&h[dst[e] >> 8], 1);
    }
    __syncthreads();
    for (int i = t; i < nbuk; i += 256) hist[i * nblk + blockIdx.x] = h[i];
}

// ---------------- pass 1: bin-scatter with LDS reorder ------------------------

__global__ __launch_bounds__(256) void binscatter_k(const int* __restrict__ src,
                                                    const int* __restrict__ dst,
                                                    const int* __restrict__ base,
                                                    unsigned int* __restrict__ binned,
                                                    int E, int nblk, int nbuk) {
    __shared__ int hloc[512];
    __shared__ int lstart[512];
    __shared__ int stmp[512];
    __shared__ unsigned int pk[EPB];
    __shared__ unsigned short bid[EPB];
    int t = threadIdx.x;
    int blk = blockIdx.x;
    int start = blk * EPB;
    int end = start + EPB; if (end > E) end = E;
    int cntE = end - start;

    for (int i = t; i < nbuk; i += 256) hloc[i] = 0;
    __syncthreads();
    for (int e = start + t; e < end; e += 256) atomicAdd(&hloc[dst[e] >> 8], 1);
    __syncthreads();
    for (int i = t; i < 512; i += 256) stmp[i] = (i < nbuk) ? hloc[i] : 0;
    __syncthreads();
    for (int off = 1; off < 512; off <<= 1) {
        int v0 = (t >= off) ? stmp[t - off] : 0;
        int v1 = stmp[t + 256 - off];
        __syncthreads();
        stmp[t] += v0;
        stmp[t + 256] += v1;
        __syncthreads();
    }
    for (int i = t; i < nbuk; i += 256) {
        int ex = stmp[i] - hloc[i];
        lstart[i] = ex;
        hloc[i] = ex;
    }
    __syncthreads();
    for (int e = start + t; e < end; e += 256) {
        int d = dst[e];
        int b = d >> 8;
        int r = atomicAdd(&hloc[b], 1);
        pk[r] = (unsigned int)src[e] | ((unsigned int)(d & 255) << 24);
        bid[r] = (unsigned short)b;
    }
    __syncthreads();
    for (int i = t; i < cntE; i += 256) {
        int b = bid[i];
        binned[base[b * nblk + blk] + (i - lstart[b])] = pk[i];
    }
}

// ---------------- pass 2: per-bucket counting sort -> rowptr, dinv, col --------

__global__ __launch_bounds__(256) void group_k(const unsigned int* __restrict__ binned,
                                               const int* __restrict__ base,
                                               int* __restrict__ rowptr,
                                               float* __restrict__ dinv,
                                               int* __restrict__ col,
                                               int nblk, int nbuk, int N, int E) {
    __shared__ int cntL[256];
    __shared__ int sc[256];
    __shared__ int cur[256];
    __shared__ int stage[SEGCAP];
    int b = blockIdx.x, t = threadIdx.x;
    int segstart = base[b * nblk];
    int segend = (b + 1 < nbuk) ? base[(b + 1) * nblk] : E;
    int seglen = segend - segstart;

    cntL[t] = 0;
    __syncthreads();
    for (int i = segstart + t; i < segend; i += 256)
        atomicAdd(&cntL[binned[i] >> 24], 1);
    __syncthreads();
    sc[t] = cntL[t];
    __syncthreads();
    for (int off = 1; off < 256; off <<= 1) {
        int v = (t >= off) ? sc[t - off] : 0;
        __syncthreads();
        sc[t] += v;
        __syncthreads();
    }
    int n = (b << 8) + t;
    if (n < N) {
        rowptr[n + 1] = segstart + sc[t];
        dinv[n] = rsqrtf((float)cntL[t] + 1.0f);
    }
    if (b == 0 && t == 0) rowptr[0] = 0;
    cur[t] = sc[t] - cntL[t];
    __syncthreads();
    if (seglen <= SEGCAP) {
        for (int i = segstart + t; i < segend; i += 256) {
            unsigned int p = binned[i];
            int r = atomicAdd(&cur[p >> 24], 1);
            stage[r] = (int)(p & 0xFFFFFFu);
        }
        __syncthreads();
        for (int i = t; i < seglen; i += 256) col[segstart + i] = stage[i];
    } else {
        for (int i = segstart + t; i < segend; i += 256) {
            unsigned int p = binned[i];
            int r = atomicAdd(&cur[p >> 24], 1);
            col[segstart + r] = (int)(p & 0xFFFFFFu);
        }
    }
}

// ------- pack W1,W2 (f32 [128][128]) into fp16 MFMA B-fragment order -----------

__global__ __launch_bounds__(256) void packW2_k(const float* __restrict__ W1,
                                                const float* __restrict__ W2,
                                                _Float16* __restrict__ Wp1,
                                                _Float16* __restrict__ Wp2) {
    const float* W = (blockIdx.x < 8) ? W1 : W2;
    _Float16* Wp = (blockIdx.x < 8) ? Wp1 : Wp2;
    int t = (blockIdx.x & 7) * 256 + threadIdx.x;   // 0..2047
    int lane = t & 63, qct = t >> 6;
    int q = qct >> 3, ct = qct & 7;
    int krow = q * 32 + (lane >> 4) * 8;
    int c = ct * 16 + (lane & 15);
#pragma unroll
    for (int j = 0; j < 8; ++j)
        Wp[(size_t)t * 8 + j] = (_Float16)W[(krow + j) * 128 + c];
}

// ------- MFMA GEMM: G = (X @ W) * dinv[row] -> fp16 [N][128] ------------------

template<typename XT>
__global__ __launch_bounds__(256) void gemm_mfma(const XT* __restrict__ X,
                                                 const _Float16* __restrict__ Wp,
                                                 const float* __restrict__ dinv,
                                                 _Float16* __restrict__ Gh, int M) {
    constexpr bool F32 = (sizeof(XT) == 4);
    __shared__ _Float16 Wl[16384];
    int t = threadIdx.x;
    for (int i = t; i < 2048; i += 256)
        *(float4*)&Wl[(size_t)i * 8] = ((const float4*)Wp)[i];

    int wid = t >> 6, lane = t & 63;
    int row0 = blockIdx.x * 64 + wid * 16;
    int arow = row0 + (lane & 15); if (arow >= M) arow = M - 1;
    int kgrp = (lane >> 4) * 8;

    half8 a[4];
    if constexpr (F32) {
#pragma unroll
        for (int q = 0; q < 4; ++q) {
            const float* p = (const float*)X + (size_t)arow * 128 + q * 32 + kgrp;
            float4 u = *(const float4*)p;
            float4 v = *(const float4*)(p + 4);
            half8 h;
            h[0] = (_Float16)u.x; h[1] = (_Float16)u.y;
            h[2] = (_Float16)u.z; h[3] = (_Float16)u.w;
            h[4] = (_Float16)v.x; h[5] = (_Float16)v.y;
            h[6] = (_Float16)v.z; h[7] = (_Float16)v.w;
            a[q] = h;
        }
    } else {
#pragma unroll
        for (int q = 0; q < 4; ++q)
            a[q] = *(const half8*)((const _Float16*)X + (size_t)arow * 128 + q * 32 + kgrp);
    }
    __syncthreads();

    f32x4 acc[8];
#pragma unroll
    for (int ct = 0; ct < 8; ++ct) acc[ct] = (f32x4){0.f, 0.f, 0.f, 0.f};

#pragma unroll
    for (int q = 0; q < 4; ++q) {
#pragma unroll
        for (int ct = 0; ct < 8; ++ct) {
            half8 b = *(const half8*)&Wl[(size_t)((q * 8 + ct) * 64 + lane) * 8];
            acc[ct] = __builtin_amdgcn_mfma_f32_16x16x32_f16(a[q], b, acc[ct], 0, 0, 0);
        }
    }

    int rbase = row0 + (lane >> 4) * 4;
#pragma unroll
    for (int reg = 0; reg < 4; ++reg) {
        int r = rbase + reg;
        if (r < M) {
            float di = dinv[r];
#pragma unroll
            for (int ct = 0; ct < 8; ++ct)
                Gh[(size_t)r * 128 + ct * 16 + (lane & 15)] = (_Float16)(acc[ct][reg] * di);
        }
    }
}

// ------- helpers ----------------------------------------------------------------

__device__ __forceinline__ void addpk(__half2* acc, float4 v) {
    const __half2* h = reinterpret_cast<const __half2*>(&v);
#pragma unroll
    for (int j = 0; j < 4; ++j) acc[j] = __hadd2(acc[j], h[j]);
}

// ------- aggregation: fp16 packed accumulate, wave/node, 4 slots x 16 lanes ----

__global__ __launch_bounds__(256) void aggregate128h(const float4* __restrict__ G4,
                                                     const float* __restrict__ dinv,
                                                     const int* __restrict__ rowptr,
                                                     const int* __restrict__ col,
                                                     const float4* __restrict__ bias4,
                                                     float4* __restrict__ OutH, int N) {
    int n = blockIdx.x * 4 + (threadIdx.x >> 6);
    if (n >= N) return;
    int lane = threadIdx.x & 63;
    int f = lane & 15;
    int slot = lane >> 4;
    int e0 = rowptr[n], e1 = rowptr[n + 1];
    __half2 acc[4];
#pragma unroll
    for (int j = 0; j < 4; ++j) acc[j] = __float2half2_rn(0.f);

    int base = e0;
    for (; base + 16 <= e1; base += 16) {
        int s0 = __builtin_nontemporal_load(&col[base + slot]);
        int s1 = __builtin_nontemporal_load(&col[base + 4 + slot]);
        int s2 = __builtin_nontemporal_load(&col[base + 8 + slot]);
        int s3 = __builtin_nontemporal_load(&col[base + 12 + slot]);
        float4 v0 = G4[(size_t)s0 * 16 + f];
        float4 v1 = G4[(size_t)s1 * 16 + f];
        float4 v2 = G4[(size_t)s2 * 16 + f];
        float4 v3 = G4[(size_t)s3 * 16 + f];
        addpk(acc, v0); addpk(acc, v1); addpk(acc, v2); addpk(acc, v3);
    }
    for (int idx = base + slot; idx < e1; idx += 4) {
        int s = __builtin_nontemporal_load(&col[idx]);
        float4 v = G4[(size_t)s * 16 + f];
        addpk(acc, v);
    }
    float a[8];
#pragma unroll
    for (int j = 0; j < 4; ++j) {
        float2 fp = __half22float2(acc[j]);
        a[2 * j] = fp.x;
        a[2 * j + 1] = fp.y;
    }
#pragma unroll
    for (int j = 0; j < 8; ++j) {
        a[j] += __shfl_xor(a[j], 16);
        a[j] += __shfl_xor(a[j], 32);
    }
    if (slot == 0) {
        float4 g = G4[(size_t)n * 16 + f];
        const __half2* sp = (const __half2*)&g;
        float di = dinv[n];
        float4 b0 = bias4[f * 2], b1 = bias4[f * 2 + 1];
        float o[8];
#pragma unroll
        for (int j = 0; j < 4; ++j) {
            float2 fp = __half22float2(sp[j]);
            o[2 * j]     = di * (a[2 * j] + fp.x);
            o[2 * j + 1] = di * (a[2 * j + 1] + fp.y);
        }
        o[0] += b0.x; o[1] += b0.y; o[2] += b0.z; o[3] += b0.w;
        o[4] += b1.x; o[5] += b1.y; o[6] += b1.z; o[7] += b1.w;
#pragma unroll
        for (int j = 0; j < 8; ++j) o[j] = fmaxf(o[j], 0.f);
        __half2 hh[4];
#pragma unroll
        for (int j = 0; j < 4; ++j) hh[j] = __floats2half2_rn(o[2 * j], o[2 * j + 1]);
        OutH[(size_t)n * 16 + f] = *(float4*)hh;
    }
}

// ------- layer-2 aggregate with FUSED layer-3 transform ------------------------

__global__ __launch_bounds__(256) void aggregate128h_w3(const float4* __restrict__ G4,
                                                        const float* __restrict__ dinv,
                                                        const int* __restrict__ rowptr,
                                                        const int* __restrict__ col,
                                                        const float4* __restrict__ bias4,
                                                        const float* __restrict__ W3,
                                                        float* __restrict__ G3, int N) {
    int n = blockIdx.x * 4 + (threadIdx.x >> 6);
    if (n >= N) return;
    int lane = threadIdx.x & 63;
    int f = lane & 15;
    int slot = lane >> 4;
    int e0 = rowptr[n], e1 = rowptr[n + 1];
    __half2 acc[4];
#pragma unroll
    for (int j = 0; j < 4; ++j) acc[j] = __float2half2_rn(0.f);

    int base = e0;
    for (; base + 16 <= e1; base += 16) {
        int s0 = __builtin_nontemporal_load(&col[base + slot]);
        int s1 = __builtin_nontemporal_load(&col[base + 4 + slot]);
        int s2 = __builtin_nontemporal_load(&col[base + 8 + slot]);
        int s3 = __builtin_nontemporal_load(&col[base + 12 + slot]);
        float4 v0 = G4[(size_t)s0 * 16 + f];
        float4 v1 = G4[(size_t)s1 * 16 + f];
        float4 v2 = G4[(size_t)s2 * 16 + f];
        float4 v3 = G4[(size_t)s3 * 16 + f];
        addpk(acc, v0); addpk(acc, v1); addpk(acc, v2); addpk(acc, v3);
    }
    for (int idx = base + slot; idx < e1; idx += 4) {
        int s = __builtin_nontemporal_load(&col[idx]);
        float4 v = G4[(size_t)s * 16 + f];
        addpk(acc, v);
    }
    float a[8];
#pragma unroll
    for (int j = 0; j < 4; ++j) {
        float2 fp = __half22float2(acc[j]);
        a[2 * j] = fp.x;
        a[2 * j + 1] = fp.y;
    }
#pragma unroll
    for (int j = 0; j < 8; ++j) {
        a[j] += __shfl_xor(a[j], 16);
        a[j] += __shfl_xor(a[j], 32);
    }
    float p0 = 0.f, p1 = 0.f;
    float di = dinv[n];
    if (slot == 0) {
        float4 g = G4[(size_t)n * 16 + f];
        const __half2* sp = (const __half2*)&g;
        float4 b0 = bias4[f * 2], b1 = bias4[f * 2 + 1];
        float o[8];
#pragma unroll
        for (int j = 0; j < 4; ++j) {
            float2 fp = __half22float2(sp[j]);
            o[2 * j]     = di * (a[2 * j] + fp.x);
            o[2 * j + 1] = di * (a[2 * j + 1] + fp.y);
        }
        o[0] += b0.x; o[1] += b0.y; o[2] += b0.z; o[3] += b0.w;
        o[4] += b1.x; o[5] += b1.y; o[6] += b1.z; o[7] += b1.w;
#pragma unroll
        for (int j = 0; j < 8; ++j) o[j] = fmaxf(o[j], 0.f);
        float w[16];
        *(float4*)&w[0]  = ((const float4*)W3)[f * 4 + 0];
        *(float4*)&w[4]  = ((const float4*)W3)[f * 4 + 1];
        *(float4*)&w[8]  = ((const float4*)W3)[f * 4 + 2];
        *(float4*)&w[12] = ((const float4*)W3)[f * 4 + 3];
#pragma unroll
        for (int j = 0; j < 8; ++j) {
            p0 += o[j] * w[2 * j];
            p1 += o[j] * w[2 * j + 1];
        }
    }
#pragma unroll
    for (int m = 1; m < 16; m <<= 1) {
        p0 += __shfl_xor(p0, m);
        p1 += __shfl_xor(p1, m);
    }
    if (lane == 0) {
        G3[(size_t)n * 2 + 0] = p0 * di;
        G3[(size_t)n * 2 + 1] = p1 * di;
    }
}

// -------- fused layer-3 aggregate + mean-pool ---------------------------------

__global__ __launch_bounds__(256) void agg2pool(const float2* __restrict__ G3,
                                                const float* __restrict__ dinv,
                                                const int* __restrict__ rowptr,
                                                const int* __restrict__ col,
                                                const float* __restrict__ b3,
                                                const int* __restrict__ batch,
                                                float* __restrict__ pool, int N) {
    __shared__ float ls[192];
    for (int i = threadIdx.x; i < 192; i += 256) ls[i] = 0.f;
    __syncthreads();
    int n = blockIdx.x * 256 + threadIdx.x;
    if (n < N) {
        float s0 = 0.f, s1 = 0.f;
        int e0 = rowptr[n], e1 = rowptr[n + 1];
        int e = e0;
        for (; e + 4 <= e1; e += 4) {
            float2 v0 = G3[__builtin_nontemporal_load(&col[e])];
            float2 v1 = G3[__builtin_nontemporal_load(&col[e + 1])];
            float2 v2 = G3[__builtin_nontemporal_load(&col[e + 2])];
            float2 v3 = G3[__builtin_nontemporal_load(&col[e + 3])];
            s0 += v0.x + v1.x + v2.x + v3.x;
            s1 += v0.y + v1.y + v2.y + v3.y;
        }
        for (; e < e1; ++e) {
            float2 v = G3[__builtin_nontemporal_load(&col[e])];
            s0 += v.x; s1 += v.y;
        }
        float2 g = G3[n];
        float di = dinv[n];
        float o0 = di * (s0 + g.x) + b3[0];
        float o1 = di * (s1 + g.y) + b3[1];
        int gb = batch[n];
        atomicAdd(&ls[gb * 3 + 0], o0);
        atomicAdd(&ls[gb * 3 + 1], o1);
        atomicAdd(&ls[gb * 3 + 2], 1.0f);
    }
    __syncthreads();
    for (int i = threadIdx.x; i < 192; i += 256)
        if (ls[i] != 0.f) atomicAdd(&pool[i], ls[i]);
}

__global__ void finalize_k(const float* __restrict__ pool, float* __restrict__ out) {
    int t = threadIdx.x;
    if (t < 128) {
        int g = t >> 1, c = t & 1;
        out[t] = pool[g * 3 + c] / fmaxf(pool[g * 3 + 2], 1.0f);
    }
}

// ---------------- launch --------------------------------------------------------

extern "C" void kernel_launch(void* const* d_in, const int* in_sizes, int n_in,
                              void* d_out, int out_size, void* d_ws, size_t ws_size,
                              hipStream_t stream) {
    const float* x   = (const float*)d_in[0];
    const int*  edge = (const int*)d_in[1];
    const int*  batch= (const int*)d_in[2];
    const float* W1  = (const float*)d_in[3];
    const float* b1  = (const float*)d_in[4];
    const float* W2  = (const float*)d_in[5];
    const float* b2  = (const float*)d_in[6];
    const float* W3  = (const float*)d_in[7];
    const float* b3  = (const float*)d_in[8];
    float* out = (float*)d_out;

    int N = in_sizes[0] / 128;
    int E = in_sizes[1] / 2;
    const int* src = edge;
    const int* dst = edge + E;

    int nblk1 = (E + EPB - 1) / EPB;
    int nbuk  = (N + 255) >> 8;
    int T     = nbuk * nblk1;
    int nb2   = (T + 255) / 256;

    char* base_ws = (char*)d_ws;
    size_t off = 0;
    auto alloc = [&](size_t bytes) -> void* {
        void* r = base_ws + off;
        off = (off + bytes + 255) & ~(size_t)255;
        return r;
    };
    _Float16*     GhA    = (_Float16*)alloc((size_t)N * 128 * 2);
    _Float16*     GhB    = (_Float16*)alloc((size_t)N * 128 * 2);
    _Float16*     Wp1    = (_Float16*)alloc(16384 * 2);
    _Float16*     Wp2    = (_Float16*)alloc(16384 * 2);
    float*        dinv   = (float*)alloc((size_t)N * 4);
    int*          rowptr = (int*)alloc((size_t)(N + 1) * 4);
    int*          col    = (int*)alloc((size_t)E * 4);
    unsigned int* binned = (unsigned int*)alloc((size_t)E * 4);
    int*          hist   = (int*)alloc((size_t)T * 4);
    int*          incl   = (int*)alloc((size_t)T * 4);
    int*          bsum   = (int*)alloc(1024 * 4);
    int*          boff   = (int*)alloc(1024 * 4);
    int*          basea  = (int*)alloc((size_t)(T + 1) * 4);
    float*        g3     = (float*)alloc((size_t)N * 2 * 4);
    float*        pool   = (float*)alloc(64 * 3 * 4);

    hipMemsetAsync(pool, 0, 64 * 3 * 4, stream);

    // W pre-packing for MFMA (single launch)
    packW2_k<<<16, 256, 0, stream>>>(W1, W2, Wp1, Wp2);

    // CSR build via 2-level bucket sort
    hist_k<<<nblk1, 256, 0, stream>>>(dst, hist, E, nblk1, nbuk);
    scan1<<<nb2, 256, 0, stream>>>(hist, incl, bsum, T);
    scan2<<<1, 1024, 0, stream>>>(bsum, boff, nb2);
    basec_k<<<nb2, 256, 0, stream>>>(incl, boff, hist, basea, T);
    binscatter_k<<<nblk1, 256, 0, stream>>>(src, dst, basea, binned, E, nblk1, nbuk);
    group_k<<<nbuk, 256, 0, stream>>>(binned, basea, rowptr, dinv, col, nblk1, nbuk, N, E);

    int gb = (N + 63) / 64;
    int ab = (N + 3) / 4;

    // layer 1 (f32 input, MFMA)
    gemm_mfma<float><<<gb, 256, 0, stream>>>(x, Wp1, dinv, GhA, N);
    aggregate128h<<<ab, 256, 0, stream>>>((const float4*)GhA, dinv, rowptr, col,
                                          (const float4*)b1, (float4*)GhB, N);
    // layer 2 (fp16 input, MFMA) + fused layer-3 transform in aggregate
    gemm_mfma<_Float16><<<gb, 256, 0, stream>>>(GhB, Wp2, dinv, GhA, N);
    aggregate128h_w3<<<ab, 256, 0, stream>>>((const float4*)GhA, dinv, rowptr, col,
                                             (const float4*)b2, W3, g3, N);
    // layer 3 aggregate + pool (fused)
    agg2pool<<<(N + 255) / 256, 256, 0, stream>>>((const float2*)g3, dinv, rowptr, col,
                                                  b3, batch, pool, N);
    finalize_k<<<1, 128, 0, stream>>>(pool, out);
}

// Round 13
// 225.863 us; speedup vs baseline: 1.1162x; 1.0697x over previous
//
#include <hip/hip_runtime.h>
#include <hip/hip_fp16.h>

#define EPB 4096        // edges per bin-scatter block
#define SEGCAP 12288    // LDS staging cap for one coarse bucket's edges

typedef __attribute__((ext_vector_type(8))) _Float16 half8;
typedef __attribute__((ext_vector_type(4))) float f32x4;
typedef __attribute__((ext_vector_type(4))) int i32x4;

// ---------------- generic scan helpers ----------------------------------------

__global__ void scan1(const int* __restrict__ v, int* __restrict__ incl,
                      int* __restrict__ bsum, int n) {
    __shared__ int tmp[256];
    int t = threadIdx.x;
    int gid = blockIdx.x * 256 + t;
    tmp[t] = (gid < n) ? v[gid] : 0;
    __syncthreads();
    for (int off = 1; off < 256; off <<= 1) {
        int x = (t >= off) ? tmp[t - off] : 0;
        __syncthreads();
        tmp[t] += x;
        __syncthreads();
    }
    if (gid < n) incl[gid] = tmp[t];
    if (t == 255) bsum[blockIdx.x] = tmp[255];
}

__global__ void scan2(const int* __restrict__ bsum, int* __restrict__ boff, int nb) {
    __shared__ int tmp[1024];
    int t = threadIdx.x;
    int orig = (t < nb) ? bsum[t] : 0;
    tmp[t] = orig;
    __syncthreads();
    for (int off = 1; off < 1024; off <<= 1) {
        int x = (t >= off) ? tmp[t - off] : 0;
        __syncthreads();
        tmp[t] += x;
        __syncthreads();
    }
    if (t < nb) boff[t] = tmp[t] - orig;
}

__global__ void basec_k(const int* __restrict__ incl, const int* __restrict__ boff,
                        const int* __restrict__ hist, int* __restrict__ base, int T) {
    int i = blockIdx.x * 256 + threadIdx.x;
    if (i < T) base[i] = incl[i] + boff[blockIdx.x] - hist[i];
}

// ---------------- pass 0: coarse histogram [bucket][block] --------------------

__global__ __launch_bounds__(256) void hist_k(const int* __restrict__ dst,
                                              int* __restrict__ hist,
                                              int E, int nblk, int nbuk) {
    __shared__ int h[512];
    int t = threadIdx.x;
    for (int i = t; i < nbuk; i += 256) h[i] = 0;
    __syncthreads();
    int start = blockIdx.x * EPB;
    int end = start + EPB; if (end > E) end = E;
    if (end - start == EPB) {
        const i32x4* dv = (const i32x4*)(dst + start);
#pragma unroll
        for (int p = 0; p < EPB / 1024; ++p) {
            i32x4 d4 = dv[t + p * 256];
            atomicAdd(&h[d4.x >> 8], 1);
            atomicAdd(&h[d4.y >> 8], 1);
            atomicAdd(&h[d4.z >> 8], 1);
            atomicAdd(&h[d4.w >> 8], 1);
        }
    } else {
        for (int e = start + t; e < end; e += 256) atomicAdd(&h[dst[e] >> 8], 1);
    }
    __syncthreads();
    for (int i = t; i < nbuk; i += 256) hist[i * nblk + blockIdx.x] = h[i];
}

// ---------------- pass 1: bin-scatter with LDS reorder ------------------------

__global__ __launch_bounds__(256) void binscatter_k(const int* __restrict__ src,
                                                    const int* __restrict__ dst,
                                                    const int* __restrict__ base,
                                                    unsigned int* __restrict__ binned,
                                                    int E, int nblk, int nbuk) {
    __shared__ int hloc[512];
    __shared__ int lstart[512];
    __shared__ int stmp[512];
    __shared__ unsigned int pk[EPB];
    __shared__ unsigned short bid[EPB];
    int t = threadIdx.x;
    int blk = blockIdx.x;
    int start = blk * EPB;
    int end = start + EPB; if (end > E) end = E;
    int cntE = end - start;

    for (int i = t; i < nbuk; i += 256) hloc[i] = 0;
    __syncthreads();
    for (int e = start + t; e < end; e += 256) atomicAdd(&hloc[dst[e] >> 8], 1);
    __syncthreads();
    for (int i = t; i < 512; i += 256) stmp[i] = (i < nbuk) ? hloc[i] : 0;
    __syncthreads();
    for (int off = 1; off < 512; off <<= 1) {
        int v0 = (t >= off) ? stmp[t - off] : 0;
        int v1 = stmp[t + 256 - off];
        __syncthreads();
        stmp[t] += v0;
        stmp[t + 256] += v1;
        __syncthreads();
    }
    for (int i = t; i < nbuk; i += 256) {
        int ex = stmp[i] - hloc[i];
        lstart[i] = ex;
        hloc[i] = ex;
    }
    __syncthreads();
    for (int e = start + t; e < end; e += 256) {
        int d = dst[e];
        int b = d >> 8;
        int r = atomicAdd(&hloc[b], 1);
        pk[r] = (unsigned int)src[e] | ((unsigned int)(d & 255) << 24);
        bid[r] = (unsigned short)b;
    }
    __syncthreads();
    for (int i = t; i < cntE; i += 256) {
        int b = bid[i];
        binned[base[b * nblk + blk] + (i - lstart[b])] = pk[i];
    }
}

// ---------------- pass 2: per-bucket counting sort -> rowptr, dinv, col --------

__global__ __launch_bounds__(256) void group_k(const unsigned int* __restrict__ binned,
                                               const int* __restrict__ base,
                                               int* __restrict__ rowptr,
                                               float* __restrict__ dinv,
                                               int* __restrict__ col,
                                               int nblk, int nbuk, int N, int E) {
    __shared__ int cntL[256];
    __shared__ int sc[256];
    __shared__ int cur[256];
    __shared__ int stage[SEGCAP];
    int b = blockIdx.x, t = threadIdx.x;
    int segstart = base[b * nblk];
    int segend = (b + 1 < nbuk) ? base[(b + 1) * nblk] : E;
    int seglen = segend - segstart;

    cntL[t] = 0;
    __syncthreads();
    for (int i = segstart + t; i < segend; i += 256)
        atomicAdd(&cntL[binned[i] >> 24], 1);
    __syncthreads();
    sc[t] = cntL[t];
    __syncthreads();
    for (int off = 1; off < 256; off <<= 1) {
        int v = (t >= off) ? sc[t - off] : 0;
        __syncthreads();
        sc[t] += v;
        __syncthreads();
    }
    int n = (b << 8) + t;
    if (n < N) {
        rowptr[n + 1] = segstart + sc[t];
        dinv[n] = rsqrtf((float)cntL[t] + 1.0f);
    }
    if (b == 0 && t == 0) rowptr[0] = 0;
    cur[t] = sc[t] - cntL[t];
    __syncthreads();
    if (seglen <= SEGCAP) {
        for (int i = segstart + t; i < segend; i += 256) {
            unsigned int p = binned[i];
            int r = atomicAdd(&cur[p >> 24], 1);
            stage[r] = (int)(p & 0xFFFFFFu);
        }
        __syncthreads();
        for (int i = t; i < seglen; i += 256) col[segstart + i] = stage[i];
    } else {
        for (int i = segstart + t; i < segend; i += 256) {
            unsigned int p = binned[i];
            int r = atomicAdd(&cur[p >> 24], 1);
            col[segstart + r] = (int)(p & 0xFFFFFFu);
        }
    }
}

// ------- pack W1,W2 (f32 [128][128]) into fp16 MFMA B-fragment order -----------

__global__ __launch_bounds__(256) void packW2_k(const float* __restrict__ W1,
                                                const float* __restrict__ W2,
                                                _Float16* __restrict__ Wp1,
                                                _Float16* __restrict__ Wp2) {
    const float* W = (blockIdx.x < 8) ? W1 : W2;
    _Float16* Wp = (blockIdx.x < 8) ? Wp1 : Wp2;
    int t = (blockIdx.x & 7) * 256 + threadIdx.x;   // 0..2047
    int lane = t & 63, qct = t >> 6;
    int q = qct >> 3, ct = qct & 7;
    int krow = q * 32 + (lane >> 4) * 8;
    int c = ct * 16 + (lane & 15);
#pragma unroll
    for (int j = 0; j < 8; ++j)
        Wp[(size_t)t * 8 + j] = (_Float16)W[(krow + j) * 128 + c];
}

// ------- MFMA GEMM: G = (X @ W) * dinv[row] -> fp16 [N][128] ------------------

template<typename XT>
__global__ __launch_bounds__(256) void gemm_mfma(const XT* __restrict__ X,
                                                 const _Float16* __restrict__ Wp,
                                                 const float* __restrict__ dinv,
                                                 _Float16* __restrict__ Gh, int M) {
    constexpr bool F32 = (sizeof(XT) == 4);
    __shared__ _Float16 Wl[16384];
    int t = threadIdx.x;
    for (int i = t; i < 2048; i += 256)
        *(float4*)&Wl[(size_t)i * 8] = ((const float4*)Wp)[i];

    int wid = t >> 6, lane = t & 63;
    int row0 = blockIdx.x * 64 + wid * 16;
    int arow = row0 + (lane & 15); if (arow >= M) arow = M - 1;
    int kgrp = (lane >> 4) * 8;

    half8 a[4];
    if constexpr (F32) {
#pragma unroll
        for (int q = 0; q < 4; ++q) {
            const float* p = (const float*)X + (size_t)arow * 128 + q * 32 + kgrp;
            float4 u = *(const float4*)p;
            float4 v = *(const float4*)(p + 4);
            half8 h;
            h[0] = (_Float16)u.x; h[1] = (_Float16)u.y;
            h[2] = (_Float16)u.z; h[3] = (_Float16)u.w;
            h[4] = (_Float16)v.x; h[5] = (_Float16)v.y;
            h[6] = (_Float16)v.z; h[7] = (_Float16)v.w;
            a[q] = h;
        }
    } else {
#pragma unroll
        for (int q = 0; q < 4; ++q)
            a[q] = *(const half8*)((const _Float16*)X + (size_t)arow * 128 + q * 32 + kgrp);
    }
    __syncthreads();

    f32x4 acc[8];
#pragma unroll
    for (int ct = 0; ct < 8; ++ct) acc[ct] = (f32x4){0.f, 0.f, 0.f, 0.f};

#pragma unroll
    for (int q = 0; q < 4; ++q) {
#pragma unroll
        for (int ct = 0; ct < 8; ++ct) {
            half8 b = *(const half8*)&Wl[(size_t)((q * 8 + ct) * 64 + lane) * 8];
            acc[ct] = __builtin_amdgcn_mfma_f32_16x16x32_f16(a[q], b, acc[ct], 0, 0, 0);
        }
    }

    int rbase = row0 + (lane >> 4) * 4;
#pragma unroll
    for (int reg = 0; reg < 4; ++reg) {
        int r = rbase + reg;
        if (r < M) {
            float di = dinv[r];
#pragma unroll
            for (int ct = 0; ct < 8; ++ct)
                Gh[(size_t)r * 128 + ct * 16 + (lane & 15)] = (_Float16)(acc[ct][reg] * di);
        }
    }
}

// ------- helpers ----------------------------------------------------------------

__device__ __forceinline__ void addpk(__half2* acc, float4 v) {
    const __half2* h = reinterpret_cast<const __half2*>(&v);
#pragma unroll
    for (int j = 0; j < 4; ++j) acc[j] = __hadd2(acc[j], h[j]);
}

// ------- aggregation: fp16 packed accumulate, wave/node, 4 slots x 16 lanes ----

__global__ __launch_bounds__(256) void aggregate128h(const float4* __restrict__ G4,
                                                     const float* __restrict__ dinv,
                                                     const int* __restrict__ rowptr,
                                                     const int* __restrict__ col,
                                                     const float4* __restrict__ bias4,
                                                     float4* __restrict__ OutH, int N) {
    int n = blockIdx.x * 4 + (threadIdx.x >> 6);
    if (n >= N) return;
    int lane = threadIdx.x & 63;
    int f = lane & 15;
    int slot = lane >> 4;
    int e0 = rowptr[n], e1 = rowptr[n + 1];
    __half2 acc[4];
#pragma unroll
    for (int j = 0; j < 4; ++j) acc[j] = __float2half2_rn(0.f);

    int base = e0;
    for (; base + 16 <= e1; base += 16) {
        int s0 = col[base + slot];
        int s1 = col[base + 4 + slot];
        int s2 = col[base + 8 + slot];
        int s3 = col[base + 12 + slot];
        float4 v0 = G4[(size_t)s0 * 16 + f];
        float4 v1 = G4[(size_t)s1 * 16 + f];
        float4 v2 = G4[(size_t)s2 * 16 + f];
        float4 v3 = G4[(size_t)s3 * 16 + f];
        addpk(acc, v0); addpk(acc, v1); addpk(acc, v2); addpk(acc, v3);
    }
    for (int idx = base + slot; idx < e1; idx += 4) {
        float4 v = G4[(size_t)col[idx] * 16 + f];
        addpk(acc, v);
    }
    float a[8];
#pragma unroll
    for (int j = 0; j < 4; ++j) {
        float2 fp = __half22float2(acc[j]);
        a[2 * j] = fp.x;
        a[2 * j + 1] = fp.y;
    }
#pragma unroll
    for (int j = 0; j < 8; ++j) {
        a[j] += __shfl_xor(a[j], 16);
        a[j] += __shfl_xor(a[j], 32);
    }
    if (slot == 0) {
        float4 g = G4[(size_t)n * 16 + f];
        const __half2* sp = (const __half2*)&g;
        float di = dinv[n];
        float4 b0 = bias4[f * 2], b1 = bias4[f * 2 + 1];
        float o[8];
#pragma unroll
        for (int j = 0; j < 4; ++j) {
            float2 fp = __half22float2(sp[j]);
            o[2 * j]     = di * (a[2 * j] + fp.x);
            o[2 * j + 1] = di * (a[2 * j + 1] + fp.y);
        }
        o[0] += b0.x; o[1] += b0.y; o[2] += b0.z; o[3] += b0.w;
        o[4] += b1.x; o[5] += b1.y; o[6] += b1.z; o[7] += b1.w;
#pragma unroll
        for (int j = 0; j < 8; ++j) o[j] = fmaxf(o[j], 0.f);
        __half2 hh[4];
#pragma unroll
        for (int j = 0; j < 4; ++j) hh[j] = __floats2half2_rn(o[2 * j], o[2 * j + 1]);
        OutH[(size_t)n * 16 + f] = *(float4*)hh;
    }
}

// ------- layer-2 aggregate with FUSED layer-3 transform ------------------------

__global__ __launch_bounds__(256) void aggregate128h_w3(const float4* __restrict__ G4,
                                                        const float* __restrict__ dinv,
                                                        const int* __restrict__ rowptr,
                                                        const int* __restrict__ col,
                                                        const float4* __restrict__ bias4,
                                                        const float* __restrict__ W3,
                                                        float* __restrict__ G3, int N) {
    int n = blockIdx.x * 4 + (threadIdx.x >> 6);
    if (n >= N) return;
    int lane = threadIdx.x & 63;
    int f = lane & 15;
    int slot = lane >> 4;
    int e0 = rowptr[n], e1 = rowptr[n + 1];
    __half2 acc[4];
#pragma unroll
    for (int j = 0; j < 4; ++j) acc[j] = __float2half2_rn(0.f);

    int base = e0;
    for (; base + 16 <= e1; base += 16) {
        int s0 = col[base + slot];
        int s1 = col[base + 4 + slot];
        int s2 = col[base + 8 + slot];
        int s3 = col[base + 12 + slot];
        float4 v0 = G4[(size_t)s0 * 16 + f];
        float4 v1 = G4[(size_t)s1 * 16 + f];
        float4 v2 = G4[(size_t)s2 * 16 + f];
        float4 v3 = G4[(size_t)s3 * 16 + f];
        addpk(acc, v0); addpk(acc, v1); addpk(acc, v2); addpk(acc, v3);
    }
    for (int idx = base + slot; idx < e1; idx += 4) {
        float4 v = G4[(size_t)col[idx] * 16 + f];
        addpk(acc, v);
    }
    float a[8];
#pragma unroll
    for (int j = 0; j < 4; ++j) {
        float2 fp = __half22float2(acc[j]);
        a[2 * j] = fp.x;
        a[2 * j + 1] = fp.y;
    }
#pragma unroll
    for (int j = 0; j < 8; ++j) {
        a[j] += __shfl_xor(a[j], 16);
        a[j] += __shfl_xor(a[j], 32);
    }
    float p0 = 0.f, p1 = 0.f;
    float di = dinv[n];
    if (slot == 0) {
        float4 g = G4[(size_t)n * 16 + f];
        const __half2* sp = (const __half2*)&g;
        float4 b0 = bias4[f * 2], b1 = bias4[f * 2 + 1];
        float o[8];
#pragma unroll
        for (int j = 0; j < 4; ++j) {
            float2 fp = __half22float2(sp[j]);
            o[2 * j]     = di * (a[2 * j] + fp.x);
            o[2 * j + 1] = di * (a[2 * j + 1] + fp.y);
        }
        o[0] += b0.x; o[1] += b0.y; o[2] += b0.z; o[3] += b0.w;
        o[4] += b1.x; o[5] += b1.y; o[6] += b1.z; o[7] += b1.w;
#pragma unroll
        for (int j = 0; j < 8; ++j) o[j] = fmaxf(o[j], 0.f);
        float w[16];
        *(float4*)&w[0]  = ((const float4*)W3)[f * 4 + 0];
        *(float4*)&w[4]  = ((const float4*)W3)[f * 4 + 1];
        *(float4*)&w[8]  = ((const float4*)W3)[f * 4 + 2];
        *(float4*)&w[12] = ((const float4*)W3)[f * 4 + 3];
#pragma unroll
        for (int j = 0; j < 8; ++j) {
            p0 += o[j] * w[2 * j];
            p1 += o[j] * w[2 * j + 1];
        }
    }
#pragma unroll
    for (int m = 1; m < 16; m <<= 1) {
        p0 += __shfl_xor(p0, m);
        p1 += __shfl_xor(p1, m);
    }
    if (lane == 0) {
        G3[(size_t)n * 2 + 0] = p0 * di;
        G3[(size_t)n * 2 + 1] = p1 * di;
    }
}

// -------- fused layer-3 aggregate + mean-pool ---------------------------------

__global__ __launch_bounds__(256) void agg2pool(const float2* __restrict__ G3,
                                                const float* __restrict__ dinv,
                                                const int* __restrict__ rowptr,
                                                const int* __restrict__ col,
                                                const float* __restrict__ b3,
                                                const int* __restrict__ batch,
                                                float* __restrict__ pool, int N) {
    __shared__ float ls[192];
    for (int i = threadIdx.x; i < 192; i += 256) ls[i] = 0.f;
    __syncthreads();
    int n = blockIdx.x * 256 + threadIdx.x;
    if (n < N) {
        float s0 = 0.f, s1 = 0.f;
        int e0 = rowptr[n], e1 = rowptr[n + 1];
        int e = e0;
        for (; e + 4 <= e1; e += 4) {
            float2 v0 = G3[col[e]];
            float2 v1 = G3[col[e + 1]];
            float2 v2 = G3[col[e + 2]];
            float2 v3 = G3[col[e + 3]];
            s0 += v0.x + v1.x + v2.x + v3.x;
            s1 += v0.y + v1.y + v2.y + v3.y;
        }
        for (; e < e1; ++e) {
            float2 v = G3[col[e]];
            s0 += v.x; s1 += v.y;
        }
        float2 g = G3[n];
        float di = dinv[n];
        float o0 = di * (s0 + g.x) + b3[0];
        float o1 = di * (s1 + g.y) + b3[1];
        int gb = batch[n];
        atomicAdd(&ls[gb * 3 + 0], o0);
        atomicAdd(&ls[gb * 3 + 1], o1);
        atomicAdd(&ls[gb * 3 + 2], 1.0f);
    }
    __syncthreads();
    for (int i = threadIdx.x; i < 192; i += 256)
        if (ls[i] != 0.f) atomicAdd(&pool[i], ls[i]);
}

__global__ void finalize_k(const float* __restrict__ pool, float* __restrict__ out) {
    int t = threadIdx.x;
    if (t < 128) {
        int g = t >> 1, c = t & 1;
        out[t] = pool[g * 3 + c] / fmaxf(pool[g * 3 + 2], 1.0f);
    }
}

// ---------------- launch --------------------------------------------------------

extern "C" void kernel_launch(void* const* d_in, const int* in_sizes, int n_in,
                              void* d_out, int out_size, void* d_ws, size_t ws_size,
                              hipStream_t stream) {
    const float* x   = (const float*)d_in[0];
    const int*  edge = (const int*)d_in[1];
    const int*  batch= (const int*)d_in[2];
    const float* W1  = (const float*)d_in[3];
    const float* b1  = (const float*)d_in[4];
    const float* W2  = (const float*)d_in[5];
    const float* b2  = (const float*)d_in[6];
    const float* W3  = (const float*)d_in[7];
    const float* b3  = (const float*)d_in[8];
    float* out = (float*)d_out;

    int N = in_sizes[0] / 128;
    int E = in_sizes[1] / 2;
    const int* src = edge;
    const int* dst = edge + E;

    int nblk1 = (E + EPB - 1) / EPB;
    int nbuk  = (N + 255) >> 8;
    int T     = nbuk * nblk1;
    int nb2   = (T + 255) / 256;

    char* base_ws = (char*)d_ws;
    size_t off = 0;
    auto alloc = [&](size_t bytes) -> void* {
        void* r = base_ws + off;
        off = (off + bytes + 255) & ~(size_t)255;
        return r;
    };
    _Float16*     GhA    = (_Float16*)alloc((size_t)N * 128 * 2);
    _Float16*     GhB    = (_Float16*)alloc((size_t)N * 128 * 2);
    _Float16*     Wp1    = (_Float16*)alloc(16384 * 2);
    _Float16*     Wp2    = (_Float16*)alloc(16384 * 2);
    float*        dinv   = (float*)alloc((size_t)N * 4);
    int*          rowptr = (int*)alloc((size_t)(N + 1) * 4);
    int*          col    = (int*)alloc((size_t)E * 4);
    unsigned int* binned = (unsigned int*)alloc((size_t)E * 4);
    int*          hist   = (int*)alloc((size_t)T * 4);
    int*          incl   = (int*)alloc((size_t)T * 4);
    int*          bsum   = (int*)alloc(1024 * 4);
    int*          boff   = (int*)alloc(1024 * 4);
    int*          basea  = (int*)alloc((size_t)(T + 1) * 4);
    float*        g3     = (float*)alloc((size_t)N * 2 * 4);
    float*        pool   = (float*)alloc(64 * 3 * 4);

    hipMemsetAsync(pool, 0, 64 * 3 * 4, stream);

    // W pre-packing for MFMA (single launch)
    packW2_k<<<16, 256, 0, stream>>>(W1, W2, Wp1, Wp2);

    // CSR build via 2-level bucket sort
    hist_k<<<nblk1, 256, 0, stream>>>(dst, hist, E, nblk1, nbuk);
    scan1<<<nb2, 256, 0, stream>>>(hist, incl, bsum, T);
    scan2<<<1, 1024, 0, stream>>>(bsum, boff, nb2);
    basec_k<<<nb2, 256, 0, stream>>>(incl, boff, hist, basea, T);
    binscatter_k<<<nblk1, 256, 0, stream>>>(src, dst, basea, binned, E, nblk1, nbuk);
    group_k<<<nbuk, 256, 0, stream>>>(binned, basea, rowptr, dinv, col, nblk1, nbuk, N, E);

    int gb = (N + 63) / 64;
    int ab = (N + 3) / 4;

    // layer 1 (f32 input, MFMA)
    gemm_mfma<float><<<gb, 256, 0, stream>>>(x, Wp1, dinv, GhA, N);
    aggregate128h<<<ab, 256, 0, stream>>>((const float4*)GhA, dinv, rowptr, col,
                                          (const float4*)b1, (float4*)GhB, N);
    // layer 2 (fp16 input, MFMA) + fused layer-3 transform in aggregate
    gemm_mfma<_Float16><<<gb, 256, 0, stream>>>(GhB, Wp2, dinv, GhA, N);
    aggregate128h_w3<<<ab, 256, 0, stream>>>((const float4*)GhA, dinv, rowptr, col,
                                             (const float4*)b2, W3, g3, N);
    // layer 3 aggregate + pool (fused)
    agg2pool<<<(N + 255) / 256, 256, 0, stream>>>((const float2*)g3, dinv, rowptr, col,
                                                  b3, batch, pool, N);
    finalize_k<<<1, 128, 0, stream>>>(pool, out);
}